// Round 1
// baseline (921.982 us; speedup 1.0000x reference)
//
#include <hip/hip_runtime.h>
#include <math.h>

#define DD 64
#define BIGF 1.0e9f

// One wave (64 lanes) per sample. Lane l owns:
//   column j = l+1 state: v[j], minv[j], way[j], p[j], used[j]
//   row    r = l+1 dual:  u[r]   (scatter-add replaced by inTree-predicated add)
// Exact f32 replication of the reference Jonker-Volgenant loop; cost matrix
// staged once in LDS (16 KB/wave), logs correctly rounded via double.
__global__ __launch_bounds__(64, 1) void lap64_kernel(
    const float* __restrict__ gamma,
    const float* __restrict__ uin,
    float* __restrict__ out)
{
    __shared__ float cost[DD * DD];
    const int l = threadIdx.x;   // lane 0..63
    const int b = blockIdx.x;    // sample

    const float lo = 1e-20f;
    const float hi = (float)(1.0 - 1e-7);

    const float* us = uin + (size_t)b * (DD * DD);

    // ---- Precompute cost = -(gamma + gumbel), gumbel = -log(-log(clip(u))) ----
    // Each log computed in double, rounded to f32 (correctly-rounded f32 log),
    // matching the reference's f32 intermediate rounding of the nested logs.
    for (int i = 0; i < DD; ++i) {
        float uu = us[i * DD + l];
        float x  = fminf(fmaxf(uu, lo), hi);
        float inner = (float)log((double)x);        // f32-rounded log(x) (negative)
        float outer = (float)log((double)(-inner)); // f32-rounded log(-inner)
        float gum = -outer;                         // * gumbel_std(=1.0) is identity
        float sc  = gamma[i * DD + l] + gum;        // f32 add, as in reference
        cost[i * DD + l] = -sc;                     // cost = -scores
    }
    __syncthreads();

    float v  = 0.0f;  // v[l+1]
    float ud = 0.0f;  // u[l+1]  (row dual)
    int   p  = 0;     // p[l+1]  (1-based row matched to column l+1; 0 = none)

    for (int i = 0; i < DD; ++i) {
        float minv = BIGF;
        int   way  = 0;
        bool  used = false;
        bool  inTree = (l == i);   // row i+1 enters tree via virtual column 0
        int   j0 = 0;
        int   i0 = i + 1;          // p[0] = i+1

        // ---- shortest augmenting path search ----
        // Each iteration consumes one unused column -> at most 64 iterations.
        for (int it = 0; it < DD + 8; ++it) {
            float u_i0 = __shfl(ud, i0 - 1);             // u[i0]
            float c    = cost[(i0 - 1) * DD + l];        // cost[i0-1][l]
            float cur  = (c - u_i0) - v;                 // ((cost - u) - v), as ref
            if (!used && (cur < minv)) { minv = cur; way = j0; }
            float masked = used ? BIGF : minv;

            // argmin over columns 1..64 with FIRST-index tie-break
            // (column 0 is always BIG and can never win)
            float bv = masked;
            #pragma unroll
            for (int off = 32; off >= 1; off >>= 1)
                bv = fminf(bv, __shfl_xor(bv, off));
            unsigned long long tie = __ballot(masked == bv);
            int j1 = __ffsll(tie);                       // lane+1 == column index
            float delta = bv;

            // dual updates (exactly the reference's where()-updates)
            if (inTree) ud += delta;                     // u[p[j]] += delta, all used j (+ col 0)
            if (used)   v    -= delta;
            else        minv -= delta;

            j0 = j1;
            int pj0 = __shfl(p, j0 - 1);
            used = used || (l == (j0 - 1));              // used[j0] set at next iter start
            if (pj0 == 0) break;                         // reached unmatched column
            i0 = pj0;
            inTree = inTree || (l == (i0 - 1));          // row i0 joins tree
        }

        // ---- augment along way[] chain ----
        for (int it = 0; it < DD + 1 && j0 != 0; ++it) {
            int jn = __shfl(way, j0 - 1);
            int pn = (jn == 0) ? (i + 1) : __shfl(p, jn - 1);
            if (l == (j0 - 1)) p = pn;
            j0 = jn;
        }
    }

    // ---- write one-hot permutation: out[b][p-1][l] = 1 ----
    float* ob = out + (size_t)b * (DD * DD);
    const int prow = p - 1;
    for (int r = 0; r < DD; ++r) {
        ob[r * DD + l] = (prow == r) ? 1.0f : 0.0f;
    }
}

extern "C" void kernel_launch(void* const* d_in, const int* in_sizes, int n_in,
                              void* d_out, int out_size, void* d_ws, size_t ws_size,
                              hipStream_t stream) {
    const float* gamma = (const float*)d_in[0];
    const float* u     = (const float*)d_in[1];
    float* out = (float*)d_out;
    const int nsamp = in_sizes[1] / (DD * DD);   // 8192
    lap64_kernel<<<dim3(nsamp), dim3(64), 0, stream>>>(gamma, u, out);
}

// Round 2
// 621.527 us; speedup vs baseline: 1.4834x; 1.4834x over previous
//
#include <hip/hip_runtime.h>
#include <math.h>

#define DD 64
#define BIGF 1.0e9f

// uniform-lane broadcast via v_readlane (no DS pipe)
__device__ __forceinline__ float bcastf(float x, int lane) {
    return __builtin_bit_cast(float, __builtin_amdgcn_readlane(__builtin_bit_cast(int, x), lane));
}

// full-wave64 min via DPP (pure VALU): row_shr 1/2/4/8 + row_bcast15/31.
// Invalid source lanes keep old value (bound_ctrl=false) -> harmless for min.
// Full min lands in lane 63; broadcast with readlane.
__device__ __forceinline__ float wave_min64(float x) {
#define STEP(ctrl)                                                                 \
    {                                                                              \
        int _t = __builtin_amdgcn_update_dpp(__builtin_bit_cast(int, x),           \
                                             __builtin_bit_cast(int, x),           \
                                             ctrl, 0xF, 0xF, false);               \
        x = fminf(x, __builtin_bit_cast(float, _t));                               \
    }
    STEP(0x111)  // row_shr:1
    STEP(0x112)  // row_shr:2
    STEP(0x114)  // row_shr:4
    STEP(0x118)  // row_shr:8
    STEP(0x142)  // row_bcast:15
    STEP(0x143)  // row_bcast:31
#undef STEP
    return bcastf(x, 63);
}

// One wave (64 lanes) per sample. Lane l owns:
//   column j = l+1 state: v[j], minv[j], way[j], p[j], used[j]
//   row    r = l+1 dual:  u[r]  (scatter-add -> inTree-predicated add)
// Bit-exact f32 replication of the reference Jonker-Volgenant trajectory.
__global__ __launch_bounds__(64, 1) void lap64_kernel(
    const float* __restrict__ gamma,
    const float* __restrict__ uin,
    float* __restrict__ out)
{
    __shared__ float cost[DD * DD];
    const int l = threadIdx.x;
    const int b = blockIdx.x;

    const float lo = 1e-20f;
    const float hi = (float)(1.0 - 1e-7);

    const float* us = uin + (size_t)b * (DD * DD);

    // ---- cost = -(gamma + gumbel), gumbel = -log(-log(clip(u))) ----
    // logs computed in double, rounded to f32 (matched reference exactly, r1)
    for (int i = 0; i < DD; ++i) {
        float uu = us[i * DD + l];
        float x  = fminf(fmaxf(uu, lo), hi);
        float inner = (float)log((double)x);
        float outer = (float)log((double)(-inner));
        float sc  = gamma[i * DD + l] + (-outer);
        cost[i * DD + l] = -sc;
    }
    __syncthreads();

    float v  = 0.0f;  // v[l+1]
    float ud = 0.0f;  // u[l+1]
    int   p  = 0;     // p[l+1] (1-based row matched to column l+1; 0 = none)

    for (int i = 0; i < DD; ++i) {
        float minv = BIGF;
        int   way  = 0;
        bool  used = false;
        bool  inTree = (l == i);     // row i+1 enters tree via virtual col 0
        int   j0 = 0;
        int   i0 = i + 1;
        float c  = cost[i * DD + l]; // row i0-1 = i, prefetched

        for (int it = 0; it <= DD; ++it) {
            float u_i0 = bcastf(ud, i0 - 1);
            float cur  = (c - u_i0) - v;          // ((cost - u) - v), as reference
            if (!used && (cur < minv)) { minv = cur; way = j0; }
            float masked = used ? BIGF : minv;

            float delta = wave_min64(masked);     // argmin value (all lanes)
            unsigned long long tie = __ballot(masked == delta);
            int j1 = __ffsll(tie);                // first-index tie-break; lane+1 = column
            j1 = __builtin_amdgcn_readfirstlane(j1);
            int pj1 = __builtin_amdgcn_readlane(p, j1 - 1);

            // issue next cost-row load ASAP; overlaps with dual updates below
            if (pj1 != 0) c = cost[(pj1 - 1) * DD + l];

            // dual updates (reference's where()-updates)
            if (inTree) ud += delta;
            if (used)   v    -= delta;
            else        minv -= delta;

            used = used || (l == (j1 - 1));
            j0 = j1;
            if (pj1 == 0) break;
            i0 = pj1;
            inTree = inTree || (l == (i0 - 1));
        }

        // ---- augment along way[] chain ----
        while (j0 != 0) {
            int jn = __builtin_amdgcn_readlane(way, j0 - 1);
            int pn = (jn == 0) ? (i + 1) : __builtin_amdgcn_readlane(p, jn - 1);
            if (l == (j0 - 1)) p = pn;
            j0 = jn;
        }
    }

    // ---- write one-hot permutation: out[b][p-1][l] = 1 ----
    float* ob = out + (size_t)b * (DD * DD);
    const int prow = p - 1;
    for (int r = 0; r < DD; ++r) {
        ob[r * DD + l] = (prow == r) ? 1.0f : 0.0f;
    }
}

extern "C" void kernel_launch(void* const* d_in, const int* in_sizes, int n_in,
                              void* d_out, int out_size, void* d_ws, size_t ws_size,
                              hipStream_t stream) {
    const float* gamma = (const float*)d_in[0];
    const float* u     = (const float*)d_in[1];
    float* out = (float*)d_out;
    const int nsamp = in_sizes[1] / (DD * DD);
    lap64_kernel<<<dim3(nsamp), dim3(64), 0, stream>>>(gamma, u, out);
}

// Round 3
// 466.055 us; speedup vs baseline: 1.9783x; 1.3336x over previous
//
#include <hip/hip_runtime.h>
#include <math.h>

#define DD 64
#define BIGF 1.0e9f

// uniform-lane broadcast via v_readlane (no DS pipe)
__device__ __forceinline__ float bcastf(float x, int lane) {
    return __builtin_bit_cast(float, __builtin_amdgcn_readlane(__builtin_bit_cast(int, x), lane));
}

// full-wave64 min via DPP (pure VALU): row_shr 1/2/4/8 + row_bcast15/31.
__device__ __forceinline__ float wave_min64(float x) {
#define STEP(ctrl)                                                                 \
    {                                                                              \
        int _t = __builtin_amdgcn_update_dpp(__builtin_bit_cast(int, x),           \
                                             __builtin_bit_cast(int, x),           \
                                             ctrl, 0xF, 0xF, false);               \
        x = fminf(x, __builtin_bit_cast(float, _t));                               \
    }
    STEP(0x111)  // row_shr:1
    STEP(0x112)  // row_shr:2
    STEP(0x114)  // row_shr:4
    STEP(0x118)  // row_shr:8
    STEP(0x142)  // row_bcast:15
    STEP(0x143)  // row_bcast:31
#undef STEP
    return bcastf(x, 63);
}

// ---- Stage: cost = -(gamma + gumbel), gumbel = -log(-log(clip(u))) ----
// logs in double, rounded to f32 (bit-matched the reference in r1/r2).
// Writes the full 8192x64x64 cost tensor into d_out (scratch).
__global__ __launch_bounds__(256) void stage_kernel(
    const float* __restrict__ gamma,
    const float* __restrict__ uin,
    float* __restrict__ cost,
    int total4)
{
    int idx = blockIdx.x * blockDim.x + threadIdx.x;
    if (idx >= total4) return;
    const float lo = 1e-20f;
    const float hi = (float)(1.0 - 1e-7);

    float4 u4 = ((const float4*)uin)[idx];
    int e = idx << 2;
    const float4 g4 = *(const float4*)(gamma + (e & (DD * DD - 1)));

    float uu[4] = {u4.x, u4.y, u4.z, u4.w};
    float gg[4] = {g4.x, g4.y, g4.z, g4.w};
    float rr[4];
#pragma unroll
    for (int k = 0; k < 4; ++k) {
        float x = fminf(fmaxf(uu[k], lo), hi);
        float inner = (float)log((double)x);
        float outer = (float)log((double)(-inner));
        float sc = gg[k] + (-outer);
        rr[k] = -sc;
    }
    float4 r4 = {rr[0], rr[1], rr[2], rr[3]};
    ((float4*)cost)[idx] = r4;
}

// ---- LAP: one wave per sample, cost rows read from global (L2/L3). ----
// Lane l owns column j=l+1 state (v,minv,way,p,used) and row r=l+1 dual u.
// Bit-exact f32 replication of the reference Jonker-Volgenant trajectory.
// Overwrites its cost region with the one-hot output at the end.
__global__ __launch_bounds__(64, 7) void lap64_kernel(float* __restrict__ cost)
{
    const int l = threadIdx.x;
    const int b = blockIdx.x;
    float* cb = cost + (size_t)b * (DD * DD);

    float v  = 0.0f;  // v[l+1]
    float ud = 0.0f;  // u[l+1]
    int   p  = 0;     // p[l+1] (1-based row matched to column l+1; 0 = none)

    for (int i = 0; i < DD; ++i) {
        float minv = BIGF;
        int   way  = 0;
        bool  used = false;
        bool  inTree = (l == i);      // row i+1 enters tree via virtual col 0
        int   j0 = 0;
        float c    = cb[i * DD + l];  // row i0-1 = i
        float u_i0 = bcastf(ud, i);   // u[i+1]

        for (int it = 0; it <= DD; ++it) {
            float cur = (c - u_i0) - v;            // ((cost - u) - v), as reference
            if (!used && (cur < minv)) { minv = cur; way = j0; }
            float masked = used ? BIGF : minv;

            float delta = wave_min64(masked);
            unsigned long long tie = __ballot(masked == delta);
            int j1 = __ffsll(tie);                 // first-index tie-break
            j1 = __builtin_amdgcn_readfirstlane(j1);
            int pj1 = __builtin_amdgcn_readlane(p, j1 - 1);

            // Prefetch next row + next u[i0] ASAP. Safe before the dual update:
            // row pj1 is not yet in the tree, so ud[pj1-1] is not modified below.
            if (pj1 != 0) {
                c    = cb[(pj1 - 1) * DD + l];
                u_i0 = bcastf(ud, pj1 - 1);
            }

            // dual updates (reference's where()-updates)
            if (inTree) ud += delta;
            if (used)   v    -= delta;
            else        minv -= delta;

            used = used || (l == (j1 - 1));
            j0 = j1;
            if (pj1 == 0) break;
            inTree = inTree || (l == (pj1 - 1));
        }

        // ---- augment along way[] chain ----
        while (j0 != 0) {
            int jn = __builtin_amdgcn_readlane(way, j0 - 1);
            int pn = (jn == 0) ? (i + 1) : __builtin_amdgcn_readlane(p, jn - 1);
            if (l == (j0 - 1)) p = pn;
            j0 = jn;
        }
    }

    // ---- overwrite cost region with one-hot permutation: out[b][p-1][l] = 1 ----
    const int prow = p - 1;
    for (int r = 0; r < DD; ++r) {
        cb[r * DD + l] = (prow == r) ? 1.0f : 0.0f;
    }
}

extern "C" void kernel_launch(void* const* d_in, const int* in_sizes, int n_in,
                              void* d_out, int out_size, void* d_ws, size_t ws_size,
                              hipStream_t stream) {
    const float* gamma = (const float*)d_in[0];
    const float* u     = (const float*)d_in[1];
    float* out = (float*)d_out;
    const int nsamp = in_sizes[1] / (DD * DD);
    const int total4 = nsamp * DD * DD / 4;

    stage_kernel<<<dim3((total4 + 255) / 256), dim3(256), 0, stream>>>(gamma, u, out, total4);
    lap64_kernel<<<dim3(nsamp), dim3(64), 0, stream>>>(out);
}